// Round 4
// baseline (475.158 us; speedup 1.0000x reference)
//
#include <hip/hip_runtime.h>
#include <hip/hip_bf16.h>

#define NATOMS 131072
#define DIM    384
#define NE     4
#define H1N    256
#define H2N    192
#define H3N    160
#define BM     32
#define NTH    256
#define NTILES (NATOMS/BM + NE)   // 4100

typedef __attribute__((ext_vector_type(8))) short bf16x8;
typedef __attribute__((ext_vector_type(4))) float f32x4;
typedef __attribute__((ext_vector_type(4))) int   i32x4;
typedef __attribute__((ext_vector_type(2))) int   i32x2;

// ---------------- ws layout (bytes) ----------------
#define WS_META   0
#define WS_TABLE  64
#define WS_PERM   (WS_TABLE + NTILES*16)
#define WS_WT1    ((WS_PERM + NATOMS*4 + 255) & ~255)
#define SZ_WT1    (NE*H1N*DIM*2)
#define WS_WT2    (WS_WT1 + SZ_WT1)
#define SZ_WT2    (NE*H2N*H1N*2)
#define WS_WT3    (WS_WT2 + SZ_WT2)
#define SZ_WT3    (NE*H3N*H2N*2)

static __device__ __forceinline__ unsigned short f2bf(float f) {
  union { __hip_bfloat16 h; unsigned short u; } v;
  v.h = __float2bfloat16(f);
  return v.u;
}
static __device__ __forceinline__ unsigned pack2(float a, float b) {
  union { __hip_bfloat162 h2; unsigned u; } v;
  v.h2 = __float22bfloat162_rn(make_float2(a, b));
  return v.u;
}
static __device__ __forceinline__ float celu1(float x) {
  return x > 0.f ? x : (__expf(x) - 1.f);
}
static __device__ __forceinline__ bf16x8 cvt8(f32x4 a, f32x4 b) {
  union { bf16x8 v; unsigned u[4]; } r;
  r.u[0] = pack2(a.x, a.y); r.u[1] = pack2(a.z, a.w);
  r.u[2] = pack2(b.x, b.y); r.u[3] = pack2(b.z, b.w);
  return r.v;
}

// forced-pipeline primitives: asm loads can't be sunk/collapsed by the
// compiler; counted vmcnt + sched_barrier(0) (rule #18) fences the MFMAs.
#define GL16(dst, base, off) \
  asm volatile("global_load_dwordx4 %0, %1, off offset:%2" \
               : "=v"(dst) : "v"(base), "n"(off))

template <int N> __device__ __forceinline__ void vmwait() {
  asm volatile("s_waitcnt vmcnt(%0)" :: "n"(N) : "memory");
  __builtin_amdgcn_sched_barrier(0);
}
static __device__ __forceinline__ void lgkm0_barrier() {
  asm volatile("s_waitcnt lgkmcnt(0)" ::: "memory");
  __builtin_amdgcn_s_barrier();   // raw barrier: vmcnt prefetch survives
}

// ---------------- prep kernels ----------------
__global__ void k_zero(int* meta) {
  if (threadIdx.x < 16) meta[threadIdx.x] = 0;
}

// Tile-transpose W[e][k][n] (fp32) -> wt[e][kk][n][32] (bf16, chunk-major).
__global__ void k_wprep(const float* __restrict__ W1, const float* __restrict__ W2,
                        const float* __restrict__ W3,
                        unsigned short* __restrict__ wt1,
                        unsigned short* __restrict__ wt2,
                        unsigned short* __restrict__ wt3) {
  __shared__ float t[32][33];
  int b = blockIdx.x;
  const float* W; unsigned short* wt; int K, NN, ntiles, idx;
  if (b < 384)      { W = W1; wt = wt1; K = 384; NN = 256; ntiles = 8; idx = b; }
  else if (b < 576) { W = W2; wt = wt2; K = 256; NN = 192; ntiles = 6; idx = b - 384; }
  else              { W = W3; wt = wt3; K = 192; NN = 160; ntiles = 5; idx = b - 576; }
  int per_e = (K / 32) * ntiles;
  int e  = idx / per_e;
  int r  = idx % per_e;
  int kt = r / ntiles, nt = r % ntiles;

  int row = threadIdx.x >> 3, c4 = (threadIdx.x & 7) * 4;
  float4 v = *(const float4*)(W + ((size_t)(e * K + kt * 32 + row) * NN + nt * 32 + c4));
  t[row][c4 + 0] = v.x; t[row][c4 + 1] = v.y;
  t[row][c4 + 2] = v.z; t[row][c4 + 3] = v.w;
  __syncthreads();

  int n = threadIdx.x >> 3, k4 = (threadIdx.x & 7) * 4;
  unsigned short o[4];
  o[0] = f2bf(t[k4 + 0][n]); o[1] = f2bf(t[k4 + 1][n]);
  o[2] = f2bf(t[k4 + 2][n]); o[3] = f2bf(t[k4 + 3][n]);
  i32x2 p; p.x = (int)(o[0] | ((unsigned)o[1] << 16));
  p.y = (int)(o[2] | ((unsigned)o[3] << 16));
  *(i32x2*)(wt + ((size_t)(e * (K / 32) + kt) * NN + nt * 32 + n) * 32 + k4) = p;
}

__global__ void k_hist(const int* __restrict__ index, int* __restrict__ meta) {
  __shared__ int h[NE];
  int t = threadIdx.x;
  if (t < NE) h[t] = 0;
  __syncthreads();
  int b0 = blockIdx.x * 1024;
  #pragma unroll
  for (int j = 0; j < 4; ++j) atomicAdd(&h[index[b0 + t + j*256]], 1);
  __syncthreads();
  if (t < NE) atomicAdd(&meta[t], h[t]);
}

__global__ void k_plan(int* __restrict__ meta, i32x4* __restrict__ table) {
  __shared__ int off[NE + 1], nt[NE + 1];
  if (threadIdx.x == 0) {
    int o = 0, t = 0;
    for (int e = 0; e < NE; ++e) {
      off[e] = o; nt[e] = t;
      o += meta[e];
      t += (meta[e] + BM - 1) / BM;
      meta[4 + e] = off[e];
    }
    off[NE] = o; nt[NE] = t;
  }
  __syncthreads();
  for (int i = threadIdx.x; i < NTILES; i += blockDim.x) {
    i32x4 v = {0, 0, 0, 0};
    for (int e = 0; e < NE; ++e) {
      if (i >= nt[e] && i < nt[e + 1]) {
        int local = i - nt[e];
        int cnt = off[e + 1] - off[e];
        int rem = cnt - local * BM;
        v.x = e; v.y = off[e] + local * BM; v.z = rem < BM ? rem : BM;
      }
    }
    table[i] = v;
  }
}

__global__ void k_scatter(const int* __restrict__ index, int* __restrict__ meta,
                          int* __restrict__ perm) {
  __shared__ int h[NE], base[NE];
  int t = threadIdx.x;
  if (t < NE) h[t] = 0;
  __syncthreads();
  int b0 = blockIdx.x * 1024;
  int eIdx[4];
  #pragma unroll
  for (int j = 0; j < 4; ++j) {
    eIdx[j] = index[b0 + t + j*256];
    atomicAdd(&h[eIdx[j]], 1);
  }
  __syncthreads();
  if (t < NE) { base[t] = atomicAdd(&meta[4 + t], h[t]); h[t] = 0; }
  __syncthreads();
  #pragma unroll
  for (int j = 0; j < 4; ++j) {
    int e = eIdx[j];
    int slot = atomicAdd(&h[e], 1);
    perm[base[e] + slot] = b0 + t + j*256;
  }
}

// ---------------- fused MLP ----------------
// 32 atoms/block, 4 waves = 2n x 2m. y^T = W^T x^T. All K-loop loads are
// asm-pipelined (W distance-1 double-buffer, X distance-3 queue) with
// counted vmcnt; zero barriers inside K-loops; raw lgkm-only barriers at
// layer boundaries so the next layer's W(0) prefetch stays in flight.
__launch_bounds__(NTH, 3)
__global__ void k_mlp(const float* __restrict__ aev,
                      const unsigned short* __restrict__ wt1,
                      const unsigned short* __restrict__ wt2,
                      const unsigned short* __restrict__ wt3,
                      const float* __restrict__ b1g,
                      const float* __restrict__ b2g,
                      const float* __restrict__ b3g,
                      const float* __restrict__ w4g,
                      const float* __restrict__ b4g,
                      const float* __restrict__ alpg,
                      const float* __restrict__ shfg,
                      const int* __restrict__ perm,
                      const i32x4* __restrict__ table,
                      float* __restrict__ out)
{
  __shared__ char smem[BM * 528];   // h1; h2 (400B rows) and h3 (336B) alias

  i32x4 tt = table[blockIdx.x];
  const int e = tt.x, start = tt.y, len = tt.z;
  if (len == 0) return;

  const int tid = threadIdx.x;
  const int l   = tid & 63;
  const int w   = tid >> 6;
  const int l15 = l & 15;
  const int lg  = l >> 4;
  const int l4o = lg * 16;
  const int r4  = lg * 4;
  const int wn  = w & 1;    // n-half
  const int wm  = w >> 1;   // m-half (16 atoms, 1 m-frag)

  const int xrow = wm * 16 + l15;
  const int ar = (xrow < len) ? perm[start + xrow] : 0;
  const char* xb = (const char*)(aev + (size_t)ar * DIM + lg * 8);

  // ================= Layer 1: 384 -> 256 =================
  f32x4 acc[8];
  bf16x8 ag[2][6];          // L2 W double-buffer (declared early for prologue)
  {
    #pragma unroll
    for (int a = 0; a < 8; ++a) acc[a] = f32x4{0.f, 0.f, 0.f, 0.f};

    const char* wb = (const char*)(wt1 + (size_t)e * (12 * 256 * 32)
                                   + (size_t)(wn * 128 + l15) * 32 + lg * 8);
    const char* wb2 = wb + 4096;
    bf16x8 af[2][8];
    f32x4  xq[3][2];

    // prologue: W(0) -> af[0]; X(0..2) -> slots 0..2
    GL16(af[0][0], wb, 0);    GL16(af[0][1], wb, 1024);
    GL16(af[0][2], wb, 2048); GL16(af[0][3], wb, 3072);
    GL16(af[0][4], wb2, 0);   GL16(af[0][5], wb2, 1024);
    GL16(af[0][6], wb2, 2048);GL16(af[0][7], wb2, 3072);
    wb += 16384; wb2 += 16384;
    GL16(xq[0][0], xb, 0);    GL16(xq[0][1], xb, 16);
    GL16(xq[1][0], xb, 128);  GL16(xq[1][1], xb, 144);
    GL16(xq[2][0], xb, 256);  GL16(xq[2][1], xb, 272);
    xb += 384;

#define L1S(CUR, NXT, QU, NW, PW, PX)                                         \
  {                                                                           \
    if (PW) {                                                                 \
      GL16(af[NXT][0], wb, 0);    GL16(af[NXT][1], wb, 1024);                 \
      GL16(af[NXT][2], wb, 2048); GL16(af[NXT][3], wb, 3072);                 \
      GL16(af[NXT][4], wb2, 0);   GL16(af[NXT][5], wb2, 1024);                \
      GL16(af[NXT][6], wb2, 2048);GL16(af[NXT][7], wb2, 3072);                \
      wb += 16384; wb2 += 16384;                                              \
    }                                                                         \
    vmwait<NW>();                                                             \
    bf16x8 bx = cvt8(xq[QU][0], xq[QU][1]);                                   \
    if (PX) { GL16(xq[QU][0], xb, 0); GL16(xq[QU][1], xb, 16); xb += 128; }   \
    acc[0] = __builtin_amdgcn_mfma_f32_16x16x32_bf16(af[CUR][0], bx, acc[0], 0,0,0); \
    acc[1] = __builtin_amdgcn_mfma_f32_16x16x32_bf16(af[CUR][1], bx, acc[1], 0,0,0); \
    acc[2] = __builtin_amdgcn_mfma_f32_16x16x32_bf16(af[CUR][2], bx, acc[2], 0,0,0); \
    acc[3] = __builtin_amdgcn_mfma_f32_16x16x32_bf16(af[CUR][3], bx, acc[3], 0,0,0); \
    acc[4] = __builtin_amdgcn_mfma_f32_16x16x32_bf16(af[CUR][4], bx, acc[4], 0,0,0); \
    acc[5] = __builtin_amdgcn_mfma_f32_16x16x32_bf16(af[CUR][5], bx, acc[5], 0,0,0); \
    acc[6] = __builtin_amdgcn_mfma_f32_16x16x32_bf16(af[CUR][6], bx, acc[6], 0,0,0); \
    acc[7] = __builtin_amdgcn_mfma_f32_16x16x32_bf16(af[CUR][7], bx, acc[7], 0,0,0); \
  }

    L1S(0,1,0,10,1,1)   // j=0
    L1S(1,0,1,10,1,1)
    L1S(0,1,2,10,1,1)
    L1S(1,0,0,10,1,1)
    L1S(0,1,1,10,1,1)
    L1S(1,0,2,10,1,1)
    L1S(0,1,0,10,1,1)
    L1S(1,0,1,10,1,1)
    L1S(0,1,2,10,1,1)   // j=8: last X prefetch (X11)
    L1S(1,0,0,10,1,0)   // j=9
    L1S(0,1,1, 8,1,0)   // j=10: last W prefetch (W11)
    L1S(1,0,2, 0,0,0)   // j=11
#undef L1S

    // L2 W(0) prefetch NOW -- overlaps the L1 epilogue and the barrier.
    const char* wc = (const char*)(wt2 + (size_t)e * (8 * 192 * 32)
                                   + (size_t)(wn * 96 + l15) * 32 + lg * 8);
    const char* wc2 = wc + 4096;
    GL16(ag[0][0], wc, 0);    GL16(ag[0][1], wc, 1024);
    GL16(ag[0][2], wc, 2048); GL16(ag[0][3], wc, 3072);
    GL16(ag[0][4], wc2, 0);   GL16(ag[0][5], wc2, 1024);
    wc += 12288; wc2 += 12288;

    // epilogue: bias + celu -> h1 (K-major [m][n], stride 528 B)
    #pragma unroll
    for (int ni = 0; ni < 8; ++ni) {
      const int nb = wn * 128 + ni * 16 + r4;
      float4 bias = *(const float4*)(b1g + e * H1N + nb);
      const int m = wm * 16 + l15;
      f32x4 v = acc[ni];
      i32x2 p;
      p.x = (int)pack2(celu1(v.x + bias.x), celu1(v.y + bias.y));
      p.y = (int)pack2(celu1(v.z + bias.z), celu1(v.w + bias.w));
      *(i32x2*)(smem + m * 528 + nb * 2) = p;
    }
    lgkm0_barrier();   // h1 visible; W2 prefetch still in flight

    // ================= Layer 2: 256 -> 192 =================
    f32x4 acc2[6];
    #pragma unroll
    for (int a = 0; a < 6; ++a) acc2[a] = f32x4{0.f, 0.f, 0.f, 0.f};

    // preload this wave's whole h1 B-slice into regs (no LDS in K-loop)
    bf16x8 bxh[8];
    {
      const char* hb = smem + (wm * 16 + l15) * 528 + l4o;
      #pragma unroll
      for (int kk = 0; kk < 8; ++kk)
        bxh[kk] = *(const bf16x8*)(hb + kk * 64);
    }
    asm volatile("s_waitcnt lgkmcnt(0)" ::: "memory");
    __builtin_amdgcn_sched_barrier(0);
    __builtin_amdgcn_s_barrier();   // after this, h1 region is reusable

#define L2S(CUR, NXT, KK, NW, PW)                                             \
  {                                                                           \
    if (PW) {                                                                 \
      GL16(ag[NXT][0], wc, 0);    GL16(ag[NXT][1], wc, 1024);                 \
      GL16(ag[NXT][2], wc, 2048); GL16(ag[NXT][3], wc, 3072);                 \
      GL16(ag[NXT][4], wc2, 0);   GL16(ag[NXT][5], wc2, 1024);                \
      wc += 12288; wc2 += 12288;                                              \
    }                                                                         \
    vmwait<NW>();                                                             \
    acc2[0] = __builtin_amdgcn_mfma_f32_16x16x32_bf16(ag[CUR][0], bxh[KK], acc2[0], 0,0,0); \
    acc2[1] = __builtin_amdgcn_mfma_f32_16x16x32_bf16(ag[CUR][1], bxh[KK], acc2[1], 0,0,0); \
    acc2[2] = __builtin_amdgcn_mfma_f32_16x16x32_bf16(ag[CUR][2], bxh[KK], acc2[2], 0,0,0); \
    acc2[3] = __builtin_amdgcn_mfma_f32_16x16x32_bf16(ag[CUR][3], bxh[KK], acc2[3], 0,0,0); \
    acc2[4] = __builtin_amdgcn_mfma_f32_16x16x32_bf16(ag[CUR][4], bxh[KK], acc2[4], 0,0,0); \
    acc2[5] = __builtin_amdgcn_mfma_f32_16x16x32_bf16(ag[CUR][5], bxh[KK], acc2[5], 0,0,0); \
  }

    L2S(0,1,0,6,1)
    L2S(1,0,1,6,1)
    L2S(0,1,2,6,1)
    L2S(1,0,3,6,1)
    L2S(0,1,4,6,1)
    L2S(1,0,5,6,1)
    L2S(0,1,6,6,1)
    L2S(1,0,7,0,0)
#undef L2S

    // L3 W(0) prefetch before the epilogue/barrier
    const char* wd = (const char*)(wt3 + (size_t)e * (6 * 160 * 32)
                                   + (size_t)(wn * 80 + l15) * 32 + lg * 8);
    const char* wd2 = wd + 4096;
    bf16x8 ah[2][5];
    GL16(ah[0][0], wd, 0);    GL16(ah[0][1], wd, 1024);
    GL16(ah[0][2], wd, 2048); GL16(ah[0][3], wd, 3072);
    GL16(ah[0][4], wd2, 0);
    wd += 10240; wd2 += 10240;

    // epilogue -> h2 (aliases h1 region, stride 400 B)
    #pragma unroll
    for (int ni = 0; ni < 6; ++ni) {
      const int nb = wn * 96 + ni * 16 + r4;
      float4 bias = *(const float4*)(b2g + e * H2N + nb);
      const int m = wm * 16 + l15;
      f32x4 v = acc2[ni];
      i32x2 p;
      p.x = (int)pack2(celu1(v.x + bias.x), celu1(v.y + bias.y));
      p.y = (int)pack2(celu1(v.z + bias.z), celu1(v.w + bias.w));
      *(i32x2*)(smem + m * 400 + nb * 2) = p;
    }
    lgkm0_barrier();   // h2 visible

    // ================= Layer 3: 192 -> 160 =================
    f32x4 acc3[5];
    #pragma unroll
    for (int a = 0; a < 5; ++a) acc3[a] = f32x4{0.f, 0.f, 0.f, 0.f};

    bf16x8 bxi[6];
    {
      const char* hb = smem + (wm * 16 + l15) * 400 + l4o;
      #pragma unroll
      for (int kk = 0; kk < 6; ++kk)
        bxi[kk] = *(const bf16x8*)(hb + kk * 64);
    }
    asm volatile("s_waitcnt lgkmcnt(0)" ::: "memory");
    __builtin_amdgcn_sched_barrier(0);
    __builtin_amdgcn_s_barrier();   // h2 region reusable

#define L3S(CUR, NXT, KK, NW, PW)                                             \
  {                                                                           \
    if (PW) {                                                                 \
      GL16(ah[NXT][0], wd, 0);    GL16(ah[NXT][1], wd, 1024);                 \
      GL16(ah[NXT][2], wd, 2048); GL16(ah[NXT][3], wd, 3072);                 \
      GL16(ah[NXT][4], wd2, 0);                                               \
      wd += 10240; wd2 += 10240;                                              \
    }                                                                         \
    vmwait<NW>();                                                             \
    acc3[0] = __builtin_amdgcn_mfma_f32_16x16x32_bf16(ah[CUR][0], bxi[KK], acc3[0], 0,0,0); \
    acc3[1] = __builtin_amdgcn_mfma_f32_16x16x32_bf16(ah[CUR][1], bxi[KK], acc3[1], 0,0,0); \
    acc3[2] = __builtin_amdgcn_mfma_f32_16x16x32_bf16(ah[CUR][2], bxi[KK], acc3[2], 0,0,0); \
    acc3[3] = __builtin_amdgcn_mfma_f32_16x16x32_bf16(ah[CUR][3], bxi[KK], acc3[3], 0,0,0); \
    acc3[4] = __builtin_amdgcn_mfma_f32_16x16x32_bf16(ah[CUR][4], bxi[KK], acc3[4], 0,0,0); \
  }

    L3S(0,1,0,5,1)
    L3S(1,0,1,5,1)
    L3S(0,1,2,5,1)
    L3S(1,0,3,5,1)
    L3S(0,1,4,5,1)
    L3S(1,0,5,0,0)
#undef L3S

    // epilogue -> h3 (aliases, stride 336 B)
    #pragma unroll
    for (int ni = 0; ni < 5; ++ni) {
      const int nb = wn * 80 + ni * 16 + r4;
      float4 bias = *(const float4*)(b3g + e * H3N + nb);
      const int m = wm * 16 + l15;
      f32x4 v = acc3[ni];
      i32x2 p;
      p.x = (int)pack2(celu1(v.x + bias.x), celu1(v.y + bias.y));
      p.y = (int)pack2(celu1(v.z + bias.z), celu1(v.w + bias.w));
      *(i32x2*)(smem + m * 336 + nb * 2) = p;
    }
    lgkm0_barrier();   // h3 visible
  }

  // ================= Layer 4: 160 -> 1 (VALU) =================
  if (tid < 4 * BM) {
    const int m = tid >> 2, sub = tid & 3;   // 4 lanes per atom
    const char* hp = smem + m * 336 + sub * 80;
    const float* wp = w4g + e * H3N + sub * 40;
    float s = 0.f;
    #pragma unroll
    for (int j = 0; j < 5; ++j) {
      i32x4 hv = *(const i32x4*)(hp + j * 16);
      float4 w0 = *(const float4*)(wp + j * 8);
      float4 w1 = *(const float4*)(wp + j * 8 + 4);
      s += __uint_as_float(((unsigned)hv.x) << 16) * w0.x;
      s += __uint_as_float(((unsigned)hv.x) & 0xffff0000u) * w0.y;
      s += __uint_as_float(((unsigned)hv.y) << 16) * w0.z;
      s += __uint_as_float(((unsigned)hv.y) & 0xffff0000u) * w0.w;
      s += __uint_as_float(((unsigned)hv.z) << 16) * w1.x;
      s += __uint_as_float(((unsigned)hv.z) & 0xffff0000u) * w1.y;
      s += __uint_as_float(((unsigned)hv.w) << 16) * w1.z;
      s += __uint_as_float(((unsigned)hv.w) & 0xffff0000u) * w1.w;
    }
    s += __shfl_xor(s, 1);
    s += __shfl_xor(s, 2);
    if (sub == 0 && m < len) {
      float y = (s + b4g[e]) * alpg[e] + shfg[e];
      out[perm[start + m]] = y;
    }
  }
}

extern "C" void kernel_launch(void* const* d_in, const int* in_sizes, int n_in,
                              void* d_out, int out_size, void* d_ws, size_t ws_size,
                              hipStream_t stream) {
  (void)in_sizes; (void)n_in; (void)out_size; (void)ws_size;
  const float* aev    = (const float*)d_in[0];
  const int*   index  = (const int*)d_in[1];
  const float* W1     = (const float*)d_in[2];
  const float* b1     = (const float*)d_in[3];
  const float* W2     = (const float*)d_in[4];
  const float* b2     = (const float*)d_in[5];
  const float* W3     = (const float*)d_in[6];
  const float* b3     = (const float*)d_in[7];
  const float* W4     = (const float*)d_in[8];
  const float* b4     = (const float*)d_in[9];
  const float* alphas = (const float*)d_in[10];
  const float* shifts = (const float*)d_in[11];
  float* out = (float*)d_out;
  char* ws = (char*)d_ws;

  int*   meta  = (int*)(ws + WS_META);
  i32x4* table = (i32x4*)(ws + WS_TABLE);
  int*   perm  = (int*)(ws + WS_PERM);
  unsigned short* wt1 = (unsigned short*)(ws + WS_WT1);
  unsigned short* wt2 = (unsigned short*)(ws + WS_WT2);
  unsigned short* wt3 = (unsigned short*)(ws + WS_WT3);

  k_zero<<<1, 64, 0, stream>>>(meta);
  k_wprep<<<696, 256, 0, stream>>>(W1, W2, W3, wt1, wt2, wt3);
  k_hist<<<NATOMS/1024, 256, 0, stream>>>(index, meta);
  k_plan<<<1, 256, 0, stream>>>(meta, table);
  k_scatter<<<NATOMS/1024, 256, 0, stream>>>(index, meta, perm);
  k_mlp<<<NTILES, NTH, 0, stream>>>(
      aev, wt1, wt2, wt3, b1, b2, b3, W4, b4, alphas, shifts, perm, table, out);
}

// Round 5
// 427.823 us; speedup vs baseline: 1.1106x; 1.1106x over previous
//
#include <hip/hip_runtime.h>
#include <hip/hip_bf16.h>

#define NATOMS 131072
#define DIM    384
#define NE     4
#define H1N    256
#define H2N    192
#define H3N    160
#define BM     64
#define NTH    256
#define NTILES (NATOMS/BM + NE)   // 2052

typedef __attribute__((ext_vector_type(8))) short bf16x8;
typedef __attribute__((ext_vector_type(4))) float f32x4;
typedef __attribute__((ext_vector_type(4))) int   i32x4;
typedef __attribute__((ext_vector_type(2))) int   i32x2;

// ---------------- ws layout (bytes) ----------------
#define WS_META   0
#define WS_TABLE  64
#define WS_PERM   (WS_TABLE + NTILES*16)
#define WS_WT1    ((WS_PERM + NATOMS*4 + 255) & ~255)
#define SZ_WT1    (NE*H1N*DIM*2)      // 786432, chunk stride 16384
#define WS_WT2    (WS_WT1 + SZ_WT1)
#define SZ_WT2    (NE*H2N*H1N*2)      // 393216, chunk stride 12288
#define WS_WT3    (WS_WT2 + SZ_WT2)
#define SZ_WT3    (NE*H3N*H2N*2 + 4096)  // 245760 + pad (L3 stages read 2KB past)

// ---------------- LDS layout (bytes) ----------------
#define L_SLOT(i) ((i)*16384)          // two 16 KB W slots (double buffer)
#define L_H       32768                // h1: 64 x 528 B  (h2 aliases: 64 x 400)
#define LDS_TOTAL (L_H + BM*528)       // 66560 -> 2 blocks/CU

static __device__ __forceinline__ unsigned short f2bf(float f) {
  union { __hip_bfloat16 h; unsigned short u; } v;
  v.h = __float2bfloat16(f);
  return v.u;
}
static __device__ __forceinline__ unsigned pack2(float a, float b) {
  union { __hip_bfloat162 h2; unsigned u; } v;
  v.h2 = __float22bfloat162_rn(make_float2(a, b));
  return v.u;
}
static __device__ __forceinline__ float celu1(float x) {
  return x > 0.f ? x : (__expf(x) - 1.f);
}
static __device__ __forceinline__ bf16x8 cvt8(f32x4 a, f32x4 b) {
  union { bf16x8 v; unsigned u[4]; } r;
  r.u[0] = pack2(a.x, a.y); r.u[1] = pack2(a.z, a.w);
  r.u[2] = pack2(b.x, b.y); r.u[3] = pack2(b.z, b.w);
  return r.v;
}

// fences / waits (rule #18: sched_barrier after asm waits; and pin issue order)
#define SCHEDB __builtin_amdgcn_sched_barrier(0)
#define VMWAIT(N) do { asm volatile("s_waitcnt vmcnt(" #N ")" ::: "memory"); SCHEDB; } while(0)
#define LGKM0  do { asm volatile("s_waitcnt lgkmcnt(0)" ::: "memory"); SCHEDB; } while(0)
#define BARRIER do { __builtin_amdgcn_s_barrier(); SCHEDB; } while(0)

// compiler-tracked async global->LDS (16B/lane); lds addr wave-uniform
#define GLDS16(gp, lp) __builtin_amdgcn_global_load_lds( \
    (const __attribute__((address_space(1))) unsigned int*)(gp), \
    (__attribute__((address_space(3))) unsigned int*)(lp), 16, 0, 0)

// ---------------- prep kernels ----------------
__global__ void k_zero(int* meta) {
  if (threadIdx.x < 16) meta[threadIdx.x] = 0;
}

// Tile-transpose W[e][k][n] (fp32) -> wt[e][kk][n][32] (bf16, chunk-major).
__global__ void k_wprep(const float* __restrict__ W1, const float* __restrict__ W2,
                        const float* __restrict__ W3,
                        unsigned short* __restrict__ wt1,
                        unsigned short* __restrict__ wt2,
                        unsigned short* __restrict__ wt3) {
  __shared__ float t[32][33];
  int b = blockIdx.x;
  const float* W; unsigned short* wt; int K, NN, ntiles, idx;
  if (b < 384)      { W = W1; wt = wt1; K = 384; NN = 256; ntiles = 8; idx = b; }
  else if (b < 576) { W = W2; wt = wt2; K = 256; NN = 192; ntiles = 6; idx = b - 384; }
  else              { W = W3; wt = wt3; K = 192; NN = 160; ntiles = 5; idx = b - 576; }
  int per_e = (K / 32) * ntiles;
  int e  = idx / per_e;
  int r  = idx % per_e;
  int kt = r / ntiles, nt = r % ntiles;

  int row = threadIdx.x >> 3, c4 = (threadIdx.x & 7) * 4;
  float4 v = *(const float4*)(W + ((size_t)(e * K + kt * 32 + row) * NN + nt * 32 + c4));
  t[row][c4 + 0] = v.x; t[row][c4 + 1] = v.y;
  t[row][c4 + 2] = v.z; t[row][c4 + 3] = v.w;
  __syncthreads();

  int n = threadIdx.x >> 3, k4 = (threadIdx.x & 7) * 4;
  unsigned short o[4];
  o[0] = f2bf(t[k4 + 0][n]); o[1] = f2bf(t[k4 + 1][n]);
  o[2] = f2bf(t[k4 + 2][n]); o[3] = f2bf(t[k4 + 3][n]);
  i32x2 p; p.x = (int)(o[0] | ((unsigned)o[1] << 16));
  p.y = (int)(o[2] | ((unsigned)o[3] << 16));
  *(i32x2*)(wt + ((size_t)(e * (K / 32) + kt) * NN + nt * 32 + n) * 32 + k4) = p;
}

__global__ void k_hist(const int* __restrict__ index, int* __restrict__ meta) {
  __shared__ int h[NE];
  int t = threadIdx.x;
  if (t < NE) h[t] = 0;
  __syncthreads();
  int b0 = blockIdx.x * 1024;
  #pragma unroll
  for (int j = 0; j < 4; ++j) atomicAdd(&h[index[b0 + t + j*256]], 1);
  __syncthreads();
  if (t < NE) atomicAdd(&meta[t], h[t]);
}

__global__ void k_plan(int* __restrict__ meta, i32x4* __restrict__ table) {
  __shared__ int off[NE + 1], nt[NE + 1];
  if (threadIdx.x == 0) {
    int o = 0, t = 0;
    for (int e = 0; e < NE; ++e) {
      off[e] = o; nt[e] = t;
      o += meta[e];
      t += (meta[e] + BM - 1) / BM;
      meta[4 + e] = off[e];
    }
    off[NE] = o; nt[NE] = t;
  }
  __syncthreads();
  for (int i = threadIdx.x; i < NTILES; i += blockDim.x) {
    i32x4 v = {0, 0, 0, 0};
    for (int e = 0; e < NE; ++e) {
      if (i >= nt[e] && i < nt[e + 1]) {
        int local = i - nt[e];
        int cnt = off[e + 1] - off[e];
        int rem = cnt - local * BM;
        v.x = e; v.y = off[e] + local * BM; v.z = rem < BM ? rem : BM;
      }
    }
    table[i] = v;
  }
}

__global__ void k_scatter(const int* __restrict__ index, int* __restrict__ meta,
                          int* __restrict__ perm) {
  __shared__ int h[NE], base[NE];
  int t = threadIdx.x;
  if (t < NE) h[t] = 0;
  __syncthreads();
  int b0 = blockIdx.x * 1024;
  int eIdx[4];
  #pragma unroll
  for (int j = 0; j < 4; ++j) {
    eIdx[j] = index[b0 + t + j*256];
    atomicAdd(&h[eIdx[j]], 1);
  }
  __syncthreads();
  if (t < NE) { base[t] = atomicAdd(&meta[4 + t], h[t]); h[t] = 0; }
  __syncthreads();
  #pragma unroll
  for (int j = 0; j < 4; ++j) {
    int e = eIdx[j];
    int slot = atomicAdd(&h[e], 1);
    perm[base[e] + slot] = b0 + t + j*256;
  }
}

// ---------------- fused MLP ----------------
// 64 atoms/block, 4 waves; wave w owns the w-th n-quarter x ALL 64 atoms
// (4 m-frags) -> 4 KB LDS-read per 16 MFMA. W tiles LDS-staged with
// global_load_lds, double-buffered, counted vmcnt, raw barriers (one/step).
// X per-lane in regs, depth-2, pinned between asm fences. h1/h2 handoff in
// LDS (bf16); L4 in fp32 via cross-wave partial buffer.
__launch_bounds__(NTH, 2)
__global__ void k_mlp(const float* __restrict__ aev,
                      const unsigned short* __restrict__ wt1,
                      const unsigned short* __restrict__ wt2,
                      const unsigned short* __restrict__ wt3,
                      const float* __restrict__ b1g,
                      const float* __restrict__ b2g,
                      const float* __restrict__ b3g,
                      const float* __restrict__ w4g,
                      const float* __restrict__ b4g,
                      const float* __restrict__ alpg,
                      const float* __restrict__ shfg,
                      const int* __restrict__ perm,
                      const i32x4* __restrict__ table,
                      float* __restrict__ out)
{
  extern __shared__ char smem[];

  i32x4 tt = table[blockIdx.x];
  const int e = tt.x, start = tt.y, len = tt.z;
  if (len == 0) return;

  const int tid = threadIdx.x;
  const int l   = tid & 63;
  const int w   = tid >> 6;        // wave = n-quarter
  const int l15 = l & 15;
  const int lg  = l >> 4;

  const char* w1c = (const char*)wt1 + (size_t)e * (12 * 16384);
  const char* w2c = (const char*)wt2 + (size_t)e * (8 * 12288);
  const char* w3c = (const char*)wt3 + (size_t)e * (6 * 10240);

#define STAGE4(GB, SLOT) do { \
    const char* _g = (GB) + w * 4096 + l * 16; \
    char* _l = smem + L_SLOT(SLOT) + w * 4096; \
    GLDS16(_g, _l); GLDS16(_g + 1024, _l + 1024); \
    GLDS16(_g + 2048, _l + 2048); GLDS16(_g + 3072, _l + 3072); \
    SCHEDB; \
  } while (0)
#define STAGE3(GB, SLOT) do { \
    const char* _g = (GB) + w * 3072 + l * 16; \
    char* _l = smem + L_SLOT(SLOT) + w * 3072; \
    GLDS16(_g, _l); GLDS16(_g + 1024, _l + 1024); GLDS16(_g + 2048, _l + 2048); \
    SCHEDB; \
  } while (0)

  // per-lane atom rows (4 m-frags, all atoms of the block)
  const float* xp[4];
  #pragma unroll
  for (int mf = 0; mf < 4; ++mf) {
    int r = mf * 16 + l15;
    int ar = (r < len) ? perm[start + r] : 0;
    xp[mf] = aev + (size_t)ar * DIM + lg * 8;
  }

  // prologue: W1(0) -> slot0; X(0),X(1) -> regs
  STAGE4(w1c, 0);
  f32x4 xq[2][4][2];
  #pragma unroll
  for (int s = 0; s < 2; ++s)
    #pragma unroll
    for (int mf = 0; mf < 4; ++mf) {
      xq[s][mf][0] = *(const f32x4*)(xp[mf] + s * 32);
      xq[s][mf][1] = *(const f32x4*)(xp[mf] + s * 32 + 4);
    }
  SCHEDB;

  // ================= Layer 1: 384 -> 256 =================
  f32x4 acc[4][4];               // [ni][mf]
  #pragma unroll
  for (int a = 0; a < 4; ++a)
    #pragma unroll
    for (int b = 0; b < 4; ++b)
      acc[a][b] = f32x4{0.f, 0.f, 0.f, 0.f};
  float4 b1v[4];

  #pragma unroll
  for (int kk = 0; kk < 12; ++kk) {
    // queue (oldest->newest) at this point: [W1(kk):4][X(kk+1):8]
    if (kk < 11) VMWAIT(8); else VMWAIT(0);   // W1(kk) (and X(kk)) complete
    BARRIER;                                   // tile kk ready for all waves
    if (kk == 11) {                            // biases BEFORE next stage (order!)
      #pragma unroll
      for (int ni = 0; ni < 4; ++ni)
        b1v[ni] = *(const float4*)(b1g + e * H1N + w * 64 + ni * 16 + lg * 4);
      SCHEDB;
    }
    if (kk < 11) STAGE4(w1c + (kk + 1) * 16384, (kk + 1) & 1);
    else         STAGE3(w2c, 0);               // L2 W(0) crosses the seam
    // consume X(kk), then refill slot with X(kk+2)
    bf16x8 bx[4];
    #pragma unroll
    for (int mf = 0; mf < 4; ++mf)
      bx[mf] = cvt8(xq[kk & 1][mf][0], xq[kk & 1][mf][1]);
    if (kk < 10) {
      #pragma unroll
      for (int mf = 0; mf < 4; ++mf) {
        xq[kk & 1][mf][0] = *(const f32x4*)(xp[mf] + (kk + 2) * 32);
        xq[kk & 1][mf][1] = *(const f32x4*)(xp[mf] + (kk + 2) * 32 + 4);
      }
      SCHEDB;
    }
    #pragma unroll
    for (int ni = 0; ni < 4; ++ni) {
      bf16x8 af = *(const bf16x8*)(smem + L_SLOT(kk & 1)
                                   + (w * 64 + ni * 16 + l15) * 64 + lg * 16);
      #pragma unroll
      for (int mf = 0; mf < 4; ++mf)
        acc[ni][mf] = __builtin_amdgcn_mfma_f32_16x16x32_bf16(
            af, bx[mf], acc[ni][mf], 0, 0, 0);
    }
  }

  // epilogue: bias + celu -> h1 [atom][n], pitch 528
  #pragma unroll
  for (int ni = 0; ni < 4; ++ni) {
    const int nb = w * 64 + ni * 16 + lg * 4;
    #pragma unroll
    for (int mf = 0; mf < 4; ++mf) {
      f32x4 v = acc[ni][mf];
      i32x2 p;
      p.x = (int)pack2(celu1(v.x + b1v[ni].x), celu1(v.y + b1v[ni].y));
      p.y = (int)pack2(celu1(v.z + b1v[ni].z), celu1(v.w + b1v[ni].w));
      *(i32x2*)(smem + L_H + (mf * 16 + l15) * 528 + nb * 2) = p;
    }
  }
  LGKM0; BARRIER;                              // h1 visible; W2(0) still in flight

  // ================= Layer 2: 256 -> 192 =================
  f32x4 acc2[3][4];
  #pragma unroll
  for (int a = 0; a < 3; ++a)
    #pragma unroll
    for (int b = 0; b < 4; ++b)
      acc2[a][b] = f32x4{0.f, 0.f, 0.f, 0.f};
  float4 b2v[3];

  #pragma unroll
  for (int c = 0; c < 8; ++c) {
    VMWAIT(0);                                 // W2(c) complete
    BARRIER;
    if (c == 7) {
      #pragma unroll
      for (int ni = 0; ni < 3; ++ni)
        b2v[ni] = *(const float4*)(b2g + e * H2N + w * 48 + ni * 16 + lg * 4);
      SCHEDB;
    }
    if (c < 7) STAGE3(w2c + (c + 1) * 12288, (c + 1) & 1);
    else       STAGE3(w3c, 0);                 // L3 W(0) crosses the seam
    bf16x8 bh[4];
    #pragma unroll
    for (int mf = 0; mf < 4; ++mf)
      bh[mf] = *(const bf16x8*)(smem + L_H + (mf * 16 + l15) * 528 + c * 64 + lg * 16);
    #pragma unroll
    for (int ni = 0; ni < 3; ++ni) {
      bf16x8 af = *(const bf16x8*)(smem + L_SLOT(c & 1)
                                   + (w * 48 + ni * 16 + l15) * 64 + lg * 16);
      #pragma unroll
      for (int mf = 0; mf < 4; ++mf)
        acc2[ni][mf] = __builtin_amdgcn_mfma_f32_16x16x32_bf16(
            af, bh[mf], acc2[ni][mf], 0, 0, 0);
    }
  }

  BARRIER;                                     // all h1 reads done (h2 aliases h1)
  #pragma unroll
  for (int ni = 0; ni < 3; ++ni) {
    const int nb = w * 48 + ni * 16 + lg * 4;
    #pragma unroll
    for (int mf = 0; mf < 4; ++mf) {
      f32x4 v = acc2[ni][mf];
      i32x2 p;
      p.x = (int)pack2(celu1(v.x + b2v[ni].x), celu1(v.y + b2v[ni].y));
      p.y = (int)pack2(celu1(v.z + b2v[ni].z), celu1(v.w + b2v[ni].w));
      *(i32x2*)(smem + L_H + (mf * 16 + l15) * 400 + nb * 2) = p;
    }
  }
  LGKM0; BARRIER;                              // h2 visible; W3(0) in flight

  // ================= Layer 3: 192 -> 160 =================
  // 10 n-frags split: wave w owns f = w, w+4, (w+8 if w<2)
  const int nf3 = (w < 2) ? 3 : 2;
  f32x4 acc3[3][4];
  #pragma unroll
  for (int a = 0; a < 3; ++a)
    #pragma unroll
    for (int b = 0; b < 4; ++b)
      acc3[a][b] = f32x4{0.f, 0.f, 0.f, 0.f};

  #pragma unroll
  for (int u = 0; u < 6; ++u) {
    VMWAIT(0);                                 // W3(u) complete
    BARRIER;
    if (u < 5) STAGE3(w3c + (u + 1) * 10240, (u + 1) & 1);
    bf16x8 bh[4];
    #pragma unroll
    for (int mf = 0; mf < 4; ++mf)
      bh[mf] = *(const bf16x8*)(smem + L_H + (mf * 16 + l15) * 400 + u * 64 + lg * 16);
    #pragma unroll
    for (int ni = 0; ni < 3; ++ni) {
      if (ni < nf3) {
        bf16x8 af = *(const bf16x8*)(smem + L_SLOT(u & 1)
                                     + ((w + ni * 4) * 16 + l15) * 64 + lg * 16);
        #pragma unroll
        for (int mf = 0; mf < 4; ++mf)
          acc3[ni][mf] = __builtin_amdgcn_mfma_f32_16x16x32_bf16(
              af, bh[mf], acc3[ni][mf], 0, 0, 0);
      }
    }
  }

  // ================= Layer 4: 160 -> 1 (fp32, cross-wave partials) ========
  BARRIER;                                     // close all LDS reads
  float part[4] = {0.f, 0.f, 0.f, 0.f};
  #pragma unroll
  for (int ni = 0; ni < 3; ++ni) {
    if (ni < nf3) {
      const int nb = (w + ni * 4) * 16 + lg * 4;
      float4 b3v = *(const float4*)(b3g + e * H3N + nb);
      float4 w4v = *(const float4*)(w4g + e * H3N + nb);
      #pragma unroll
      for (int mf = 0; mf < 4; ++mf) {
        f32x4 v = acc3[ni][mf];
        part[mf] += celu1(v.x + b3v.x) * w4v.x + celu1(v.y + b3v.y) * w4v.y
                  + celu1(v.z + b3v.z) * w4v.z + celu1(v.w + b3v.w) * w4v.w;
      }
    }
  }
  #pragma unroll
  for (int mf = 0; mf < 4; ++mf) {
    part[mf] += __shfl_xor(part[mf], 16);
    part[mf] += __shfl_xor(part[mf], 32);
  }
  float* pb = (float*)smem;                    // reuse slot0 region (1 KB)
  if (lg == 0) {
    #pragma unroll
    for (int mf = 0; mf < 4; ++mf) pb[w * 64 + mf * 16 + l15] = part[mf];
  }
  LGKM0; BARRIER;
  if (tid < BM && tid < len) {
    float s = pb[tid] + pb[64 + tid] + pb[128 + tid] + pb[192 + tid];
    float y = (s + b4g[e]) * alpg[e] + shfg[e];
    out[perm[start + tid]] = y;
  }
#undef STAGE4
#undef STAGE3
}

extern "C" void kernel_launch(void* const* d_in, const int* in_sizes, int n_in,
                              void* d_out, int out_size, void* d_ws, size_t ws_size,
                              hipStream_t stream) {
  (void)in_sizes; (void)n_in; (void)out_size; (void)ws_size;
  const float* aev    = (const float*)d_in[0];
  const int*   index  = (const int*)d_in[1];
  const float* W1     = (const float*)d_in[2];
  const float* b1     = (const float*)d_in[3];
  const float* W2     = (const float*)d_in[4];
  const float* b2     = (const float*)d_in[5];
  const float* W3     = (const float*)d_in[6];
  const float* b3     = (const float*)d_in[7];
  const float* W4     = (const float*)d_in[8];
  const float* b4     = (const float*)d_in[9];
  const float* alphas = (const float*)d_in[10];
  const float* shifts = (const float*)d_in[11];
  float* out = (float*)d_out;
  char* ws = (char*)d_ws;

  int*   meta  = (int*)(ws + WS_META);
  i32x4* table = (i32x4*)(ws + WS_TABLE);
  int*   perm  = (int*)(ws + WS_PERM);
  unsigned short* wt1 = (unsigned short*)(ws + WS_WT1);
  unsigned short* wt2 = (unsigned short*)(ws + WS_WT2);
  unsigned short* wt3 = (unsigned short*)(ws + WS_WT3);

  hipFuncSetAttribute((const void*)k_mlp,
                      hipFuncAttributeMaxDynamicSharedMemorySize, LDS_TOTAL);

  k_zero<<<1, 64, 0, stream>>>(meta);
  k_wprep<<<696, 256, 0, stream>>>(W1, W2, W3, wt1, wt2, wt3);
  k_hist<<<NATOMS/1024, 256, 0, stream>>>(index, meta);
  k_plan<<<1, 256, 0, stream>>>(meta, table);
  k_scatter<<<NATOMS/1024, 256, 0, stream>>>(index, meta, perm);
  k_mlp<<<NTILES, NTH, LDS_TOTAL, stream>>>(
      aev, wt1, wt2, wt3, b1, b2, b3, W4, b4, alphas, shifts, perm, table, out);
}

// Round 6
// 395.629 us; speedup vs baseline: 1.2010x; 1.0814x over previous
//
#include <hip/hip_runtime.h>
#include <hip/hip_bf16.h>

#define NATOMS 131072
#define DIM    384
#define NE     4
#define H1N    256
#define H2N    192
#define H3N    160
#define BM     128
#define NTH    512
#define NTILES (NATOMS/BM + NE)   // 1028

typedef __attribute__((ext_vector_type(8))) short bf16x8;
typedef __attribute__((ext_vector_type(4))) float f32x4;
typedef __attribute__((ext_vector_type(4))) int   i32x4;
typedef __attribute__((ext_vector_type(2))) int   i32x2;

// ---------------- ws layout (bytes) ----------------
#define WS_META   0
#define WS_TABLE  64
#define WS_PERM   (WS_TABLE + NTILES*16)
#define WS_WT1    ((WS_PERM + NATOMS*4 + 255) & ~255)
#define SZ_WT1    (NE*12*16384)        // all tiles padded to 16 KB
#define WS_WT2    (WS_WT1 + SZ_WT1)
#define SZ_WT2    (NE*8*16384)
#define WS_WT3    (WS_WT2 + SZ_WT2)
#define SZ_WT3    (NE*6*16384)

// ---------------- LDS layout (bytes) ----------------
#define L_X   0                        // X ring: 3 x 16 KB ([seg8][atom128]x16B)
#define L_W   49152                    // W dbuf: 2 x 16 KB ([n256][64B])
#define L_H   81920                    // h1: 128 x 528 (h2 aliases: 128 x 400)
#define LDS_TOTAL (L_H + BM*528)       // 149504

static __device__ __forceinline__ unsigned short f2bf(float f) {
  union { __hip_bfloat16 h; unsigned short u; } v;
  v.h = __float2bfloat16(f);
  return v.u;
}
static __device__ __forceinline__ unsigned pack2(float a, float b) {
  union { __hip_bfloat162 h2; unsigned u; } v;
  v.h2 = __float22bfloat162_rn(make_float2(a, b));
  return v.u;
}
static __device__ __forceinline__ float celu1(float x) {
  return x > 0.f ? x : (__expf(x) - 1.f);
}
static __device__ __forceinline__ bf16x8 cvt8(f32x4 a, f32x4 b) {
  union { bf16x8 v; unsigned u[4]; } r;
  r.u[0] = pack2(a.x, a.y); r.u[1] = pack2(a.z, a.w);
  r.u[2] = pack2(b.x, b.y); r.u[3] = pack2(b.z, b.w);
  return r.v;
}

#define SCHEDB __builtin_amdgcn_sched_barrier(0)
#define VMWAIT(N) do { asm volatile("s_waitcnt vmcnt(" #N ")" ::: "memory"); SCHEDB; } while(0)
#define LGKM0  do { asm volatile("s_waitcnt lgkmcnt(0)" ::: "memory"); SCHEDB; } while(0)
#define BARRIER do { __builtin_amdgcn_s_barrier(); SCHEDB; } while(0)

#define GLDS16(gp, lp) __builtin_amdgcn_global_load_lds( \
    (const __attribute__((address_space(1))) unsigned int*)(gp), \
    (__attribute__((address_space(3))) unsigned int*)(lp), 16, 0, 0)

// stage one 16 KB tile: 512 threads x 2 x 16 B (linear both sides)
#define STAGE_TILE(gbase, lbase) do { \
    GLDS16((gbase) + tid * 16,        (lbase) + tid * 16); \
    GLDS16((gbase) + 8192 + tid * 16, (lbase) + 8192 + tid * 16); \
    SCHEDB; \
  } while (0)
// stage X chunk kk into ring slot rs: per-lane gathered rows, LDS [seg][atom]
#define STAGE_X(kk, rs) do { \
    GLDS16(xsrc + (kk) * 128,      smem + L_X + (rs) * 16384 + tid * 16); \
    GLDS16(xsrc + (kk) * 128 + 64, smem + L_X + (rs) * 16384 + 8192 + tid * 16); \
    SCHEDB; \
  } while (0)

// ---------------- prep kernels ----------------
__global__ void k_zero(int* meta) {
  if (threadIdx.x < 16) meta[threadIdx.x] = 0;
}

// W[e][k][n] fp32 -> 16 KB tiles: wt[tile][n(256 rows)][32k bf16 = 64 B]
__global__ void k_wprep(const float* __restrict__ W1, const float* __restrict__ W2,
                        const float* __restrict__ W3,
                        unsigned short* __restrict__ wt1,
                        unsigned short* __restrict__ wt2,
                        unsigned short* __restrict__ wt3) {
  int b = blockIdx.x;
  const float* W; unsigned short* base; int K, NN, e, kt;
  if (b < 48)      { e = b / 12; kt = b % 12; W = W1; base = wt1 + ((size_t)(e * 12 + kt)) * 8192; K = 384; NN = 256; }
  else if (b < 80) { int i = b - 48; e = i / 8; kt = i % 8; W = W2; base = wt2 + ((size_t)(e * 8 + kt)) * 8192; K = 256; NN = 192; }
  else             { int i = b - 80; e = i / 6; kt = i % 6; W = W3; base = wt3 + ((size_t)(e * 6 + kt)) * 8192; K = 192; NN = 160; }
  int n = threadIdx.x;
  if (n >= NN) return;
  float v[32];
  #pragma unroll
  for (int k = 0; k < 32; ++k)
    v[k] = W[((size_t)(e * K + kt * 32 + k)) * NN + n];
  #pragma unroll
  for (int g = 0; g < 4; ++g) {
    i32x4 p;
    p.x = (int)pack2(v[g*8+0], v[g*8+1]);
    p.y = (int)pack2(v[g*8+2], v[g*8+3]);
    p.z = (int)pack2(v[g*8+4], v[g*8+5]);
    p.w = (int)pack2(v[g*8+6], v[g*8+7]);
    *(i32x4*)(base + n * 32 + g * 8) = p;
  }
}

__global__ void k_hist(const int* __restrict__ index, int* __restrict__ meta) {
  __shared__ int h[NE];
  int t = threadIdx.x;
  if (t < NE) h[t] = 0;
  __syncthreads();
  int b0 = blockIdx.x * 1024;
  #pragma unroll
  for (int j = 0; j < 4; ++j) atomicAdd(&h[index[b0 + t + j*256]], 1);
  __syncthreads();
  if (t < NE) atomicAdd(&meta[t], h[t]);
}

__global__ void k_plan(int* __restrict__ meta, i32x4* __restrict__ table) {
  __shared__ int off[NE + 1], nt[NE + 1];
  if (threadIdx.x == 0) {
    int o = 0, t = 0;
    for (int e = 0; e < NE; ++e) {
      off[e] = o; nt[e] = t;
      o += meta[e];
      t += (meta[e] + BM - 1) / BM;
      meta[4 + e] = off[e];
    }
    off[NE] = o; nt[NE] = t;
  }
  __syncthreads();
  for (int i = threadIdx.x; i < NTILES; i += blockDim.x) {
    i32x4 v = {0, 0, 0, 0};
    for (int e = 0; e < NE; ++e) {
      if (i >= nt[e] && i < nt[e + 1]) {
        int local = i - nt[e];
        int cnt = off[e + 1] - off[e];
        int rem = cnt - local * BM;
        v.x = e; v.y = off[e] + local * BM; v.z = rem < BM ? rem : BM;
      }
    }
    table[i] = v;
  }
}

__global__ void k_scatter(const int* __restrict__ index, int* __restrict__ meta,
                          int* __restrict__ perm) {
  __shared__ int h[NE], base[NE];
  int t = threadIdx.x;
  if (t < NE) h[t] = 0;
  __syncthreads();
  int b0 = blockIdx.x * 1024;
  int eIdx[4];
  #pragma unroll
  for (int j = 0; j < 4; ++j) {
    eIdx[j] = index[b0 + t + j*256];
    atomicAdd(&h[eIdx[j]], 1);
  }
  __syncthreads();
  if (t < NE) { base[t] = atomicAdd(&meta[4 + t], h[t]); h[t] = 0; }
  __syncthreads();
  #pragma unroll
  for (int j = 0; j < 4; ++j) {
    int e = eIdx[j];
    int slot = atomicAdd(&h[e], 1);
    perm[base[e] + slot] = b0 + t + j*256;
  }
}

// ---------------- fused MLP ----------------
// 128 atoms/block, 8 waves = 4 n-quarters (wq) x 2 m-halves (mh).
// X gathered to LDS ONCE per block (ring depth 3, [seg][atom] layout);
// W tiles LDS-staged with global_load_lds. Every K-step waits vmcnt(2)
// (2-step runway); layer seams pre-stage next layer's W into freed slots.
__launch_bounds__(NTH, 2)
__global__ void k_mlp(const float* __restrict__ aev,
                      const char* __restrict__ wt1c,
                      const char* __restrict__ wt2c,
                      const char* __restrict__ wt3c,
                      const float* __restrict__ b1g,
                      const float* __restrict__ b2g,
                      const float* __restrict__ b3g,
                      const float* __restrict__ w4g,
                      const float* __restrict__ b4g,
                      const float* __restrict__ alpg,
                      const float* __restrict__ shfg,
                      const int* __restrict__ perm,
                      const i32x4* __restrict__ table,
                      float* __restrict__ out)
{
  extern __shared__ char smem[];

  i32x4 tt = table[blockIdx.x];
  const int e = tt.x, start = tt.y, len = tt.z;
  if (len == 0) return;

  const int tid = threadIdx.x;
  const int l   = tid & 63;
  const int w   = tid >> 6;
  const int wq  = w & 3;           // n-quarter
  const int mh  = w >> 2;          // m-half (64 atoms)
  const int l15 = l & 15;
  const int lg  = l >> 4;

  // ---- hoist ALL small loads to the top so later compiler-inserted
  //      waits never drain the staging FIFO ----
  float4 b1v[4], b2v[3], b3v[3], w4v[3];
  #pragma unroll
  for (int ni = 0; ni < 4; ++ni)
    b1v[ni] = *(const float4*)(b1g + e * H1N + wq * 64 + ni * 16 + lg * 4);
  #pragma unroll
  for (int ni = 0; ni < 3; ++ni)
    b2v[ni] = *(const float4*)(b2g + e * H2N + wq * 48 + ni * 16 + lg * 4);
  const int nf3 = (wq < 2) ? 3 : 2;
  int frag3[3];
  frag3[0] = wq * 2; frag3[1] = wq * 2 + 1; frag3[2] = (wq < 2) ? (8 + wq) : 0;
  #pragma unroll
  for (int i = 0; i < 3; ++i) {
    b3v[i] = *(const float4*)(b3g + e * H3N + frag3[i] * 16 + lg * 4);
    w4v[i] = *(const float4*)(w4g + e * H3N + frag3[i] * 16 + lg * 4);
  }
  const float b4s = b4g[e], alps = alpg[e], shfs = shfg[e];

  // per-thread gather source: atom a = tid&127, seg base s0 = tid>>7
  const int a0 = tid & 127;
  const int row = (a0 < len) ? perm[start + a0] : perm[start];
  const char* xsrc = (const char*)aev + (size_t)row * (DIM * 4) + (tid >> 7) * 16;

  const char* w1c = wt1c + (size_t)e * (12 * 16384);
  const char* w2c = wt2c + (size_t)e * (8 * 16384);
  const char* w3c = wt3c + (size_t)e * (6 * 16384);

  // prologue: W1_0 -> slotA; X0 -> r0; X1 -> r1
  STAGE_TILE(w1c, smem + L_W);
  STAGE_X(0, 0);
  STAGE_X(1, 1);

  // ================= Layer 1: 384 -> 256 =================
  f32x4 acc[4][4];                 // [nf][mf]
  #pragma unroll
  for (int a = 0; a < 4; ++a)
    #pragma unroll
    for (int b = 0; b < 4; ++b)
      acc[a][b] = f32x4{0.f, 0.f, 0.f, 0.f};

  #pragma unroll
  for (int kk = 0; kk < 12; ++kk) {
    VMWAIT(2);                     // W1_kk + X_kk done; newest stage in flight
    BARRIER;
    if (kk < 11) STAGE_TILE(w1c + (kk + 1) * 16384, smem + L_W + ((kk + 1) & 1) * 16384);
    if (kk <= 9)       STAGE_X(kk + 2, (kk + 2) % 3);
    else if (kk == 10) STAGE_TILE(w2c, smem + L_X);                 // W2_0 -> r0
    else               STAGE_TILE(w2c + 16384, smem + L_X + 16384); // W2_1 -> r1

    const char* xs = smem + L_X + (kk % 3) * 16384;
    bf16x8 bx[4];
    #pragma unroll
    for (int mf = 0; mf < 4; ++mf) {
      const int atom = mh * 64 + mf * 16 + l15;
      f32x4 lo = *(const f32x4*)(xs + (2 * lg) * 2048 + atom * 16);
      f32x4 hi = *(const f32x4*)(xs + (2 * lg + 1) * 2048 + atom * 16);
      bx[mf] = cvt8(lo, hi);
    }
    const char* wsl = smem + L_W + (kk & 1) * 16384;
    #pragma unroll
    for (int nf = 0; nf < 4; ++nf) {
      bf16x8 af = *(const bf16x8*)(wsl + (wq * 64 + nf * 16 + l15) * 64 + lg * 16);
      #pragma unroll
      for (int mf = 0; mf < 4; ++mf)
        acc[nf][mf] = __builtin_amdgcn_mfma_f32_16x16x32_bf16(
            af, bx[mf], acc[nf][mf], 0, 0, 0);
    }
  }

  // epilogue: bias+celu -> h1 [atom][n] pitch 528
  #pragma unroll
  for (int ni = 0; ni < 4; ++ni) {
    const int nb = wq * 64 + ni * 16 + lg * 4;
    #pragma unroll
    for (int mf = 0; mf < 4; ++mf) {
      const int atom = mh * 64 + mf * 16 + l15;
      f32x4 v = acc[ni][mf];
      i32x2 p;
      p.x = (int)pack2(celu1(v.x + b1v[ni].x), celu1(v.y + b1v[ni].y));
      p.y = (int)pack2(celu1(v.z + b1v[ni].z), celu1(v.w + b1v[ni].w));
      *(i32x2*)(smem + L_H + atom * 528 + nb * 2) = p;
    }
  }
  LGKM0; BARRIER;                  // h1 visible; W2_0/W2_1 still in flight

  // ================= Layer 2: 256 -> 192 =================
  f32x4 acc2[3][4];
  #pragma unroll
  for (int a = 0; a < 3; ++a)
    #pragma unroll
    for (int b = 0; b < 4; ++b)
      acc2[a][b] = f32x4{0.f, 0.f, 0.f, 0.f};

  #pragma unroll
  for (int c = 0; c < 8; ++c) {
    VMWAIT(2);                     // W2_c ready; W2_{c+1} in flight
    BARRIER;
    if (c < 6)       STAGE_TILE(w2c + (c + 2) * 16384, smem + L_X + ((c + 2) % 3) * 16384);
    else if (c == 6) STAGE_TILE(w3c, smem + L_W);                   // W3_0 -> A
    else             STAGE_TILE(w3c + 16384, smem + L_W + 16384);   // W3_1 -> B

    bf16x8 bh[4];
    #pragma unroll
    for (int mf = 0; mf < 4; ++mf) {
      const int atom = mh * 64 + mf * 16 + l15;
      bh[mf] = *(const bf16x8*)(smem + L_H + atom * 528 + c * 64 + lg * 16);
    }
    const char* wsl = smem + L_X + (c % 3) * 16384;
    #pragma unroll
    for (int nf = 0; nf < 3; ++nf) {
      bf16x8 af = *(const bf16x8*)(wsl + (wq * 48 + nf * 16 + l15) * 64 + lg * 16);
      #pragma unroll
      for (int mf = 0; mf < 4; ++mf)
        acc2[nf][mf] = __builtin_amdgcn_mfma_f32_16x16x32_bf16(
            af, bh[mf], acc2[nf][mf], 0, 0, 0);
    }
  }

  BARRIER;                         // close all h1 reads (h2 aliases h1)
  #pragma unroll
  for (int ni = 0; ni < 3; ++ni) {
    const int nb = wq * 48 + ni * 16 + lg * 4;
    #pragma unroll
    for (int mf = 0; mf < 4; ++mf) {
      const int atom = mh * 64 + mf * 16 + l15;
      f32x4 v = acc2[ni][mf];
      i32x2 p;
      p.x = (int)pack2(celu1(v.x + b2v[ni].x), celu1(v.y + b2v[ni].y));
      p.y = (int)pack2(celu1(v.z + b2v[ni].z), celu1(v.w + b2v[ni].w));
      *(i32x2*)(smem + L_H + atom * 400 + nb * 2) = p;
    }
  }
  LGKM0; BARRIER;                  // h2 visible; W3_0/W3_1 in flight

  // ================= Layer 3: 192 -> 160 =================
  f32x4 acc3[3][4];
  #pragma unroll
  for (int a = 0; a < 3; ++a)
    #pragma unroll
    for (int b = 0; b < 4; ++b)
      acc3[a][b] = f32x4{0.f, 0.f, 0.f, 0.f};

  #pragma unroll
  for (int u = 0; u < 6; ++u) {
    if (u < 5) { VMWAIT(2); } else { VMWAIT(0); }
    BARRIER;
    if (u < 4) {
      const int s = (u + 2) % 3;   // ring {A, B, r0}
      char* dst = (s == 0) ? (smem + L_W) : (s == 1) ? (smem + L_W + 16384) : (smem + L_X);
      STAGE_TILE(w3c + (u + 2) * 16384, dst);
    }
    bf16x8 bh[4];
    #pragma unroll
    for (int mf = 0; mf < 4; ++mf) {
      const int atom = mh * 64 + mf * 16 + l15;
      bh[mf] = *(const bf16x8*)(smem + L_H + atom * 400 + u * 64 + lg * 16);
    }
    const int s = u % 3;
    const char* wsl = (s == 0) ? (smem + L_W) : (s == 1) ? (smem + L_W + 16384) : (smem + L_X);
    #pragma unroll
    for (int i = 0; i < 3; ++i) {
      if (i < nf3) {
        bf16x8 af = *(const bf16x8*)(wsl + (frag3[i] * 16 + l15) * 64 + lg * 16);
        #pragma unroll
        for (int mf = 0; mf < 4; ++mf)
          acc3[i][mf] = __builtin_amdgcn_mfma_f32_16x16x32_bf16(
              af, bh[mf], acc3[i][mf], 0, 0, 0);
      }
    }
  }

  // ================= Layer 4: 160 -> 1 (fp32 partials) =================
  BARRIER;                         // close W/X-slot reads before pb overwrite
  float part[4] = {0.f, 0.f, 0.f, 0.f};
  #pragma unroll
  for (int i = 0; i < 3; ++i) {
    if (i < nf3) {
      #pragma unroll
      for (int mf = 0; mf < 4; ++mf) {
        f32x4 v = acc3[i][mf];
        part[mf] += celu1(v.x + b3v[i].x) * w4v[i].x
                  + celu1(v.y + b3v[i].y) * w4v[i].y
                  + celu1(v.z + b3v[i].z) * w4v[i].z
                  + celu1(v.w + b3v[i].w) * w4v[i].w;
      }
    }
  }
  #pragma unroll
  for (int mf = 0; mf < 4; ++mf) {
    part[mf] += __shfl_xor(part[mf], 16);
    part[mf] += __shfl_xor(part[mf], 32);
  }
  float* pb = (float*)(smem + L_X);              // 8x64 floats = 2 KB
  if (lg == 0) {
    #pragma unroll
    for (int mf = 0; mf < 4; ++mf) pb[w * 64 + mf * 16 + l15] = part[mf];
  }
  LGKM0; BARRIER;
  if (tid < BM && tid < len) {
    const int hb = (tid >> 6) * 4, lo = tid & 63;
    float s = pb[(hb + 0) * 64 + lo] + pb[(hb + 1) * 64 + lo]
            + pb[(hb + 2) * 64 + lo] + pb[(hb + 3) * 64 + lo];
    out[perm[start + tid]] = (s + b4s) * alps + shfs;
  }
}

extern "C" void kernel_launch(void* const* d_in, const int* in_sizes, int n_in,
                              void* d_out, int out_size, void* d_ws, size_t ws_size,
                              hipStream_t stream) {
  (void)in_sizes; (void)n_in; (void)out_size; (void)ws_size;
  const float* aev    = (const float*)d_in[0];
  const int*   index  = (const int*)d_in[1];
  const float* W1     = (const float*)d_in[2];
  const float* b1     = (const float*)d_in[3];
  const float* W2     = (const float*)d_in[4];
  const float* b2     = (const float*)d_in[5];
  const float* W3     = (const float*)d_in[6];
  const float* b3     = (const float*)d_in[7];
  const float* W4     = (const float*)d_in[8];
  const float* b4     = (const float*)d_in[9];
  const float* alphas = (const float*)d_in[10];
  const float* shifts = (const float*)d_in[11];
  float* out = (float*)d_out;
  char* ws = (char*)d_ws;

  int*   meta  = (int*)(ws + WS_META);
  i32x4* table = (i32x4*)(ws + WS_TABLE);
  int*   perm  = (int*)(ws + WS_PERM);
  unsigned short* wt1 = (unsigned short*)(ws + WS_WT1);
  unsigned short* wt2 = (unsigned short*)(ws + WS_WT2);
  unsigned short* wt3 = (unsigned short*)(ws + WS_WT3);

  hipFuncSetAttribute((const void*)k_mlp,
                      hipFuncAttributeMaxDynamicSharedMemorySize, LDS_TOTAL);

  k_zero<<<1, 64, 0, stream>>>(meta);
  k_wprep<<<104, 256, 0, stream>>>(W1, W2, W3, wt1, wt2, wt3);
  k_hist<<<NATOMS/1024, 256, 0, stream>>>(index, meta);
  k_plan<<<1, 256, 0, stream>>>(meta, table);
  k_scatter<<<NATOMS/1024, 256, 0, stream>>>(index, meta, perm);
  k_mlp<<<NTILES, NTH, LDS_TOTAL, stream>>>(
      aev, (const char*)wt1, (const char*)wt2, (const char*)wt3,
      b1, b2, b3, W4, b4, alphas, shifts, perm, table, out);
}